// Round 1
// baseline (644.538 us; speedup 1.0000x reference)
//
#include <hip/hip_runtime.h>
#include <hip/hip_bf16.h>

#define D 128
#define EPSV 1e-5f

static inline int cdiv(int a, int b) { return (a + b - 1) / b; }

// ---------------- edge preprocessing ----------------

__global__ void edge_deg_hist(const int* __restrict__ col, const float* __restrict__ ea,
                              float* __restrict__ deg, int* __restrict__ cnt, int E_) {
    int e = blockIdx.x * blockDim.x + threadIdx.x;
    if (e >= E_) return;
    int c = col[e];
    atomicAdd(&deg[c], ea[e]);
    atomicAdd(&cnt[c], 1);
}

__global__ void dis_kernel(const float* __restrict__ deg, float* __restrict__ dis, int n) {
    int i = blockIdx.x * blockDim.x + threadIdx.x;
    if (i >= n) return;
    float dg = deg[i];
    dis[i] = dg > 0.f ? rsqrtf(fmaxf(dg, EPSV)) : 0.f;
}

// 3-kernel exclusive scan over cnt[N] (chunk = 1024)
__global__ void scan_chunk_sums(const int* __restrict__ cnt, int* __restrict__ bsum, int n) {
    __shared__ int sm[1024];
    int i = blockIdx.x * 1024 + threadIdx.x;
    sm[threadIdx.x] = (i < n) ? cnt[i] : 0;
    __syncthreads();
    for (int off = 512; off > 0; off >>= 1) {
        if (threadIdx.x < off) sm[threadIdx.x] += sm[threadIdx.x + off];
        __syncthreads();
    }
    if (threadIdx.x == 0) bsum[blockIdx.x] = sm[0];
}

__global__ void scan_tops(const int* __restrict__ bsum, int* __restrict__ bo, int nb,
                          int* __restrict__ offs, int n, int E_) {
    if (threadIdx.x == 0 && blockIdx.x == 0) {
        int run = 0;
        for (int b = 0; b < nb; ++b) { bo[b] = run; run += bsum[b]; }
        offs[n] = E_;
    }
}

__global__ void scan_final(const int* __restrict__ cnt, const int* __restrict__ bo,
                           int* __restrict__ offs, int* __restrict__ cursor, int n) {
    __shared__ int sm[1024];
    int tid = threadIdx.x;
    int i = blockIdx.x * 1024 + tid;
    int v = (i < n) ? cnt[i] : 0;
    sm[tid] = v;
    __syncthreads();
    for (int off = 1; off < 1024; off <<= 1) {
        int t = (tid >= off) ? sm[tid - off] : 0;
        __syncthreads();
        sm[tid] += t;
        __syncthreads();
    }
    if (i < n) {
        int excl = sm[tid] - v + bo[blockIdx.x];
        offs[i] = excl;
        cursor[i] = excl;
    }
}

__global__ void reorder_kernel(const int* __restrict__ row, const int* __restrict__ col,
                               const float* __restrict__ ea, const float* __restrict__ dis,
                               int* __restrict__ cursor, int* __restrict__ csr_row,
                               float* __restrict__ csr_w, int E_) {
    int e = blockIdx.x * blockDim.x + threadIdx.x;
    if (e >= E_) return;
    int r = row[e], c = col[e];
    float w = dis[r] * ea[e] * dis[c];
    int p = atomicAdd(&cursor[c], 1);
    csr_row[p] = r;
    csr_w[p] = w;
}

// ---------------- batch norm ----------------

template <bool GATHER>
__global__ __launch_bounds__(128) void bn_stats(const float* __restrict__ src,
                                                const int* __restrict__ idx,
                                                float* __restrict__ sums,
                                                float* __restrict__ sumsq, int n) {
    int d = threadIdx.x;
    float s = 0.f, s2 = 0.f;
    for (int i = blockIdx.x; i < n; i += gridDim.x) {
        int r = GATHER ? idx[i] : i;
        float v = src[(long)r * D + d];
        s += v;
        s2 += v * v;
    }
    atomicAdd(&sums[d], s);
    atomicAdd(&sumsq[d], s2);
}

__global__ void bn_finalize(const float* __restrict__ sums, const float* __restrict__ sumsq,
                            const float* __restrict__ gamma, const float* __restrict__ beta,
                            float* __restrict__ scale, float* __restrict__ shift, float n) {
    int d = threadIdx.x;
    float mean = sums[d] / n;
    float var = sumsq[d] / n - mean * mean;
    float rstd = rsqrtf(var + EPSV);
    float sc = gamma[d] * rstd;
    scale[d] = sc;
    shift[d] = beta[d] - mean * sc;
}

// ---------------- GEMM: h = (src*scale+shift) @ W ----------------
// block: 256 threads, 32 rows/block; x-tile transposed in LDS (stride 36 for
// 16B-aligned float4 reads, conflict-free); W streamed from L2 (64 KB resident).

template <bool GATHER>
__global__ __launch_bounds__(256) void gemm_bn(const float* __restrict__ src,
                                               const int* __restrict__ idx,
                                               const float* __restrict__ scale,
                                               const float* __restrict__ shift,
                                               const float* __restrict__ W,
                                               float* __restrict__ out, int n) {
    __shared__ float xsT[128 * 36];  // [k][r], 18 KB
    int r0 = blockIdx.x * 32;
    int tid = threadIdx.x;
    for (int it = 0; it < 16; ++it) {
        int flat = it * 256 + tid;  // 0..4095
        int r = flat >> 7;          // 0..31
        int k = flat & 127;
        int gr = r0 + r;
        float v = 0.f;
        if (gr < n) {
            int srow = GATHER ? idx[gr] : gr;
            v = src[(long)srow * D + k] * scale[k] + shift[k];
        }
        xsT[k * 36 + r] = v;
    }
    __syncthreads();
    int c = tid & 127;
    int half = tid >> 7;  // 0/1 -> rows [half*16, half*16+16)
    float acc[16];
#pragma unroll
    for (int j = 0; j < 16; ++j) acc[j] = 0.f;
    int rbase = half * 16;
    for (int k = 0; k < 128; ++k) {
        float wv = W[k * D + c];
        const float4* xp = (const float4*)&xsT[k * 36 + rbase];
#pragma unroll
        for (int q = 0; q < 4; ++q) {
            float4 xv = xp[q];
            acc[q * 4 + 0] += xv.x * wv;
            acc[q * 4 + 1] += xv.y * wv;
            acc[q * 4 + 2] += xv.z * wv;
            acc[q * 4 + 3] += xv.w * wv;
        }
    }
#pragma unroll
    for (int j = 0; j < 16; ++j) {
        int gr = r0 + rbase + j;
        if (gr < n) out[(long)gr * D + c] = acc[j];
    }
}

// ---------------- aggregation: x[i] = relu(b + sum_e w_e * h[row_e]) ----------------
// 2 nodes per 256-thread block; 128 threads = feature dim; coalesced 512B row gathers.

__global__ __launch_bounds__(256) void agg_kernel(const float* __restrict__ h,
                                                  const int* __restrict__ csr_row,
                                                  const float* __restrict__ csr_w,
                                                  const int* __restrict__ offs,
                                                  const float* __restrict__ bias,
                                                  float* __restrict__ xout, int n) {
    int node = blockIdx.x * 2 + (threadIdx.x >> 7);
    int d = threadIdx.x & 127;
    if (node >= n) return;
    int p0 = offs[node], p1 = offs[node + 1];
    float acc = bias[d];
    for (int p = p0; p < p1; ++p) {
        int r = csr_row[p];
        float w = csr_w[p];
        acc += w * h[(long)r * D + d];
    }
    xout[(long)node * D + d] = fmaxf(acc, 0.f);
}

// ---------------- segment boundaries + softmax pooling ----------------

__global__ void bounds_kernel(const int* __restrict__ batch, int* __restrict__ start, int n,
                              int G_) {
    int g = blockIdx.x * blockDim.x + threadIdx.x;
    if (g > G_) return;
    int lo = 0, hi = n;
    while (lo < hi) {
        int mid = (lo + hi) >> 1;
        if (batch[mid] < g) lo = mid + 1;
        else hi = mid;
    }
    start[g] = lo;
}

__global__ __launch_bounds__(128) void pool_kernel(const float* __restrict__ tfidf,
                                                   const int* __restrict__ start,
                                                   const float* __restrict__ x,
                                                   float* __restrict__ out) {
    int g = blockIdx.x;
    int s0 = start[g], s1 = start[g + 1];
    int tid = threadIdx.x;
    if (s1 <= s0) {
        out[g * D + tid] = 0.f;
        return;
    }
    __shared__ float red[128];
    // pass 1: segment max of tfidf
    float m = -1e30f;
    for (int i = s0 + tid; i < s1; i += 128) m = fmaxf(m, tfidf[i]);
    red[tid] = m;
    __syncthreads();
    for (int off = 64; off > 0; off >>= 1) {
        if (tid < off) red[tid] = fmaxf(red[tid], red[tid + off]);
        __syncthreads();
    }
    m = red[0];
    __syncthreads();
    // pass 2: sum of exp
    float s = 0.f;
    for (int i = s0 + tid; i < s1; i += 128) s += __expf(tfidf[i] - m);
    red[tid] = s;
    __syncthreads();
    for (int off = 64; off > 0; off >>= 1) {
        if (tid < off) red[tid] += red[tid + off];
        __syncthreads();
    }
    s = red[0];
    // pass 3: weighted feature sum; thread = feature d
    float acc = 0.f;
    for (int i = s0; i < s1; ++i) {
        acc += __expf(tfidf[i] - m) * x[(long)i * D + tid];
    }
    out[g * D + tid] = acc / s;
}

// ---------------- launch ----------------

extern "C" void kernel_launch(void* const* d_in, const int* in_sizes, int n_in, void* d_out,
                              int out_size, void* d_ws, size_t ws_size, hipStream_t stream) {
    const int N = in_sizes[0];
    const int E = in_sizes[4];
    const int G = out_size / D;

    const int* x_index = (const int*)d_in[0];
    const float* tfidf = (const float*)d_in[1];
    const int* ei_row = (const int*)d_in[2];
    const int* ei_col = ei_row + E;
    const int* batch = (const int*)d_in[3];
    const float* edge_attr = (const float*)d_in[4];
    const float* emb = (const float*)d_in[5];
    const float* gamma1 = (const float*)d_in[6];
    const float* beta1 = (const float*)d_in[7];
    const float* W1 = (const float*)d_in[8];
    const float* b1 = (const float*)d_in[9];
    const float* gamma2 = (const float*)d_in[10];
    const float* beta2 = (const float*)d_in[11];
    const float* W2 = (const float*)d_in[12];
    const float* b2 = (const float*)d_in[13];
    float* out = (float*)d_out;

    // ---- workspace carve (256B aligned) ----
    size_t off = 0;
    char* base = (char*)d_ws;
    auto carve = [&](size_t bytes) -> void* {
        void* p = base + off;
        off = (off + bytes + 255) & ~(size_t)255;
        return p;
    };
    float* bufA = (float*)carve((size_t)N * D * 4);  // h (gemm output)
    float* bufB = (float*)carve((size_t)N * D * 4);  // x (layer output)
    int* csr_row = (int*)carve((size_t)E * 4);
    float* csr_w = (float*)carve((size_t)E * 4);
    // contiguous zero region: deg[N] | cnt[N] | sumsA[256] | sumsB[256]
    float* deg = (float*)carve((size_t)(2 * N + 512) * 4);
    int* cnt = (int*)(deg + N);
    float* sumsA = (float*)(cnt + N);      // sums1[128], sumsq1[128]
    float* sumsB = sumsA + 256;            // sums2[128], sumsq2[128]
    float* dis = (float*)carve((size_t)N * 4);
    int* offs = (int*)carve((size_t)(N + 1) * 4);
    int* cursor = (int*)carve((size_t)N * 4);
    int* bsum = (int*)carve(256 * 4);
    int* bo = (int*)carve(256 * 4);
    int* start = (int*)carve((size_t)(G + 1) * 4);
    float* scale1 = (float*)carve(D * 4);
    float* shift1 = (float*)carve(D * 4);
    float* scale2 = (float*)carve(D * 4);
    float* shift2 = (float*)carve(D * 4);
    (void)ws_size;
    (void)n_in;

    // ---- zero accumulators ----
    hipMemsetAsync(deg, 0, (size_t)(2 * N + 512) * 4, stream);

    // ---- edge preprocessing: deg, dis, CSR ----
    edge_deg_hist<<<cdiv(E, 256), 256, 0, stream>>>(ei_col, edge_attr, deg, cnt, E);
    dis_kernel<<<cdiv(N, 256), 256, 0, stream>>>(deg, dis, N);
    int nb = cdiv(N, 1024);
    scan_chunk_sums<<<nb, 1024, 0, stream>>>(cnt, bsum, N);
    scan_tops<<<1, 1, 0, stream>>>(bsum, bo, nb, offs, N, E);
    scan_final<<<nb, 1024, 0, stream>>>(cnt, bo, offs, cursor, N);
    reorder_kernel<<<cdiv(E, 256), 256, 0, stream>>>(ei_row, ei_col, edge_attr, dis, cursor,
                                                     csr_row, csr_w, E);

    // ---- layer 1: bn(emb[x_index]) @ W1 -> agg -> relu -> bufB ----
    bn_stats<true><<<512, 128, 0, stream>>>(emb, x_index, sumsA, sumsA + 128, N);
    bn_finalize<<<1, 128, 0, stream>>>(sumsA, sumsA + 128, gamma1, beta1, scale1, shift1,
                                       (float)N);
    gemm_bn<true><<<cdiv(N, 32), 256, 0, stream>>>(emb, x_index, scale1, shift1, W1, bufA, N);
    agg_kernel<<<cdiv(N, 2), 256, 0, stream>>>(bufA, csr_row, csr_w, offs, b1, bufB, N);

    // ---- layer 2: bn(bufB) @ W2 -> agg -> relu -> bufB ----
    bn_stats<false><<<512, 128, 0, stream>>>(bufB, nullptr, sumsB, sumsB + 128, N);
    bn_finalize<<<1, 128, 0, stream>>>(sumsB, sumsB + 128, gamma2, beta2, scale2, shift2,
                                       (float)N);
    gemm_bn<false><<<cdiv(N, 32), 256, 0, stream>>>(bufB, nullptr, scale2, shift2, W2, bufA, N);
    agg_kernel<<<cdiv(N, 2), 256, 0, stream>>>(bufA, csr_row, csr_w, offs, b2, bufB, N);

    // ---- softmax pooling ----
    bounds_kernel<<<cdiv(G + 1, 256), 256, 0, stream>>>(batch, start, N, G);
    pool_kernel<<<G, 128, 0, stream>>>(tfidf, start, bufB, out);
}